// Round 11
// baseline (216.241 us; speedup 1.0000x reference)
//
#include <hip/hip_runtime.h>
#include <math.h>

#define NV 20
#define NC 64
#define NSTATES (1u << 20)
#define TOPK 10
#define NBLK 256             // mixer/ptop blocks (1 per CU)
#define NB1 256              // fallback ptop blocks
#define NCAND (NBLK * TOPK)  // 2560

// ---------------------------------------------------------------------------
// Grid barrier (R6 pattern, validated correct in R6/R7): one counter per sync
// point, zeroed by hipMemsetAsync pre-launch. Requires co-residency
// (guaranteed by hipLaunchCooperativeKernel).
// ---------------------------------------------------------------------------
__device__ __forceinline__ void gbar(unsigned* bar) {
  __syncthreads();
  if (threadIdx.x == 0) {
    __threadfence();
    atomicAdd(bar, 1u);
    while (__hip_atomic_load(bar, __ATOMIC_RELAXED,
                             __HIP_MEMORY_SCOPE_AGENT) < (unsigned)NBLK) {
      __builtin_amdgcn_s_sleep(2);
    }
    __threadfence();
  }
  __syncthreads();
}

// ---------------------------------------------------------------------------
// K1: costs + ph0 (validated chunked numerics). 256 blocks x 512 threads.
// ---------------------------------------------------------------------------
__global__ __launch_bounds__(512) void k_costs(const float* __restrict__ C,
                                               float* __restrict__ costs,
                                               float* __restrict__ ph0,
                                               const float* __restrict__ gamma,
                                               double* __restrict__ scal,
                                               unsigned* __restrict__ ctr) {
    __shared__ float CT[17][NC];
    __shared__ float lowT[8][NC];
    const int tid = threadIdx.x;

    if (blockIdx.x == 0) {
        if (tid < 8) scal[tid] = 0.0;
        if (tid == 8) *ctr = 0u;
    }

    for (int e = tid; e < 17 * NC; e += 512) {
        int k = e / NC, c = e % NC;
        CT[k][c] = C[c * NV + (16 - k)];
    }
    for (int e = tid; e < 8 * NC; e += 512) {
        int m = e >> 6, c = e & 63;
        float v = 0.0f;
        if (m & 1) v += C[c * NV + 19];
        if (m & 2) v += C[c * NV + 18];
        if (m & 4) v += C[c * NV + 17];
        lowT[m][c] = v;
    }
    __syncthreads();

    unsigned t = blockIdx.x * 512u + (unsigned)tid;   // < 2^17, 8 states each
    float g0 = gamma[0];

    float cost[8];
    #pragma unroll
    for (int s = 0; s < 8; ++s)
        cost[s] = 0.1f * (float)__popc(t * 8u + (unsigned)s);

    #pragma unroll
    for (int cc = 0; cc < 4; ++cc) {       // 16 constraints per chunk
        float4 bb[4];
        #pragma unroll
        for (int q = 0; q < 4; ++q) bb[q] = make_float4(-1.f, -1.f, -1.f, -1.f);
        #pragma unroll
        for (int k = 0; k < 17; ++k) {     // i-bit (k+3) == t-bit k
            float bf = (float)((t >> k) & 1u);
            const float4* row = ((const float4*)(&CT[k][0])) + 4 * cc;
            #pragma unroll
            for (int q = 0; q < 4; ++q) {
                float4 cv = row[q];
                bb[q].x = fmaf(bf, cv.x, bb[q].x);
                bb[q].y = fmaf(bf, cv.y, bb[q].y);
                bb[q].z = fmaf(bf, cv.z, bb[q].z);
                bb[q].w = fmaf(bf, cv.w, bb[q].w);
            }
        }
        #pragma unroll
        for (int s = 0; s < 8; ++s) {
            const float4* lrow = ((const float4*)(&lowT[s][0])) + 4 * cc;
            #pragma unroll
            for (int q = 0; q < 4; ++q) {
                float4 lv = lrow[q];
                float4 v;
                v.x = bb[q].x + lv.x; v.y = bb[q].y + lv.y;
                v.z = bb[q].z + lv.z; v.w = bb[q].w + lv.w;
                float r;
                r = fmaxf(v.x, 0.f); cost[s] = fmaf(r, r, cost[s]);
                r = fmaxf(v.y, 0.f); cost[s] = fmaf(r, r, cost[s]);
                r = fmaxf(v.z, 0.f); cost[s] = fmaf(r, r, cost[s]);
                r = fmaxf(v.w, 0.f); cost[s] = fmaf(r, r, cost[s]);
            }
        }
    }

    float4* co = (float4*)(costs + (size_t)t * 8u);
    co[0] = make_float4(cost[0], cost[1], cost[2], cost[3]);
    co[1] = make_float4(cost[4], cost[5], cost[6], cost[7]);
    float ph[8];
    #pragma unroll
    for (int s = 0; s < 8; ++s) ph[s] = 0x1p-10f * cosf(g0 * cost[s]);
    float4* po = (float4*)(ph0 + (size_t)t * 8u);
    po[0] = make_float4(ph[0], ph[1], ph[2], ph[3]);
    po[1] = make_float4(ph[4], ph[5], ph[6], ph[7]);
}

// ---------------------------------------------------------------------------
// K2: fused mix0 + mix1 (one grid barrier). pin_own and costs held in regs
// across layers. Math sequence bitwise-identical to the validated k_mix<0>,
// k_mix<1> chain.
// ---------------------------------------------------------------------------
template <bool ALB>
__global__ __launch_bounds__(1024, 4) void k_mix01(
    float* __restrict__ A,            // in: ph0, out: pm2
    const float* __restrict__ costs,
    float* __restrict__ B,            // pm1 staging
    const float* __restrict__ gamma,
    const float* __restrict__ beta,
    double* __restrict__ scal,
    unsigned* __restrict__ bars) {
  __shared__ float4 tile[1024];
  __shared__ double dpart[16];
  const unsigned lq = threadIdx.x;
  const unsigned i4 = blockIdx.x * 1024u + lq;
  const float s0 = 0.1f * sinf(beta[0]);
  const float s1 = 0.1f * sinf(beta[1]);
  const float g1 = gamma[1], g2 = gamma[2];
  const float4 c = ((const float4*)costs)[i4];

  // ================= layer 0 =================
  float4 own = ((const float4*)A)[i4];
  tile[lq] = own;
  float4 gv[8];
  #pragma unroll
  for (int p = 19; p >= 12; --p) gv[19 - p] = ((const float4*)A)[i4 ^ (1u << (p - 2))];
  __syncthreads();

  float4 nb = make_float4(0.f, 0.f, 0.f, 0.f);
  #pragma unroll
  for (int u = 0; u < 8; ++u) {
    nb.x += gv[u].x; nb.y += gv[u].y; nb.z += gv[u].z; nb.w += gv[u].w;
  }
  #pragma unroll
  for (int p = 11; p >= 2; --p) {
    float4 v = tile[lq ^ (1u << (p - 2))];
    nb.x += v.x; nb.y += v.y; nb.z += v.z; nb.w += v.w;
  }
  nb.x += own.z; nb.y += own.w; nb.z += own.x; nb.w += own.y;
  nb.x += own.y; nb.y += own.x; nb.z += own.w; nb.w += own.z;

  float4 m;
  m.x = 1.0f * fmaf(s0, nb.x, own.x);
  m.y = 1.0f * fmaf(s0, nb.y, own.y);
  m.z = 1.0f * fmaf(s0, nb.z, own.z);
  m.w = 1.0f * fmaf(s0, nb.w, own.w);

  double ss = (double)m.x * m.x + (double)m.y * m.y +
              (double)m.z * m.z + (double)m.w * m.w;
  #pragma unroll
  for (int off = 32; off > 0; off >>= 1) ss += __shfl_down(ss, off);
  if ((lq & 63) == 0) dpart[lq >> 6] = ss;
  __syncthreads();
  if (lq == 0) {
    double tt = 0.0;
    #pragma unroll
    for (int w = 0; w < 16; ++w) tt += dpart[w];
    atomicAdd(&scal[0], tt);
  }

  float4 o;                       // pm1
  o.x = m.x * cosf(g1 * c.x);
  o.y = m.y * cosf(g1 * c.y);
  o.z = m.z * cosf(g1 * c.z);
  o.w = m.w * cosf(g1 * c.w);
  if (ALB) ((float4*)B)[i4] = o;
  else {
    B[4u * i4 + 0] = o.x; B[4u * i4 + 1] = o.y;
    B[4u * i4 + 2] = o.z; B[4u * i4 + 3] = o.w;
  }

  gbar(bars + 0);

  // ================= layer 1 =================
  tile[lq] = o;
  #pragma unroll
  for (int p = 19; p >= 12; --p) {
    unsigned j4 = i4 ^ (1u << (p - 2));
    if (ALB) gv[19 - p] = ((const float4*)B)[j4];
    else {
      gv[19 - p].x = B[4u * j4 + 0]; gv[19 - p].y = B[4u * j4 + 1];
      gv[19 - p].z = B[4u * j4 + 2]; gv[19 - p].w = B[4u * j4 + 3];
    }
  }
  __syncthreads();

  nb = make_float4(0.f, 0.f, 0.f, 0.f);
  #pragma unroll
  for (int u = 0; u < 8; ++u) {
    nb.x += gv[u].x; nb.y += gv[u].y; nb.z += gv[u].z; nb.w += gv[u].w;
  }
  #pragma unroll
  for (int p = 11; p >= 2; --p) {
    float4 v = tile[lq ^ (1u << (p - 2))];
    nb.x += v.x; nb.y += v.y; nb.z += v.z; nb.w += v.w;
  }
  nb.x += o.z; nb.y += o.w; nb.z += o.x; nb.w += o.y;
  nb.x += o.y; nb.y += o.x; nb.z += o.w; nb.w += o.z;

  const float prevscale = (float)(1.0 / sqrt(scal[0]));
  m.x = prevscale * fmaf(s1, nb.x, o.x);
  m.y = prevscale * fmaf(s1, nb.y, o.y);
  m.z = prevscale * fmaf(s1, nb.z, o.z);
  m.w = prevscale * fmaf(s1, nb.w, o.w);

  ss = (double)m.x * m.x + (double)m.y * m.y +
       (double)m.z * m.z + (double)m.w * m.w;
  #pragma unroll
  for (int off = 32; off > 0; off >>= 1) ss += __shfl_down(ss, off);
  if ((lq & 63) == 0) dpart[lq >> 6] = ss;
  __syncthreads();
  if (lq == 0) {
    double tt = 0.0;
    #pragma unroll
    for (int w = 0; w < 16; ++w) tt += dpart[w];
    atomicAdd(&scal[1], tt);
  }

  float4 o2;                      // pm2
  o2.x = m.x * cosf(g2 * c.x);
  o2.y = m.y * cosf(g2 * c.y);
  o2.z = m.z * cosf(g2 * c.z);
  o2.w = m.w * cosf(g2 * c.w);
  ((float4*)A)[i4] = o2;
}

// ---------------------------------------------------------------------------
// K3: fused mix2 + probs + top-k (one grid barrier + last-block ticket).
// m2 stays in registers; B eliminated. Top-k/merge code from the validated
// R6 1024-thread stages.
// ---------------------------------------------------------------------------
__global__ __launch_bounds__(1024, 4) void k_mix2top(
    const float* __restrict__ A,      // pm2
    const float* __restrict__ costs,
    const float* __restrict__ beta,
    float* __restrict__ out,
    double* __restrict__ scal,
    unsigned long long* __restrict__ cand,
    unsigned* __restrict__ bars,
    unsigned* __restrict__ ctr) {
  __shared__ float4 tile[1024];
  __shared__ double dpart[16];
  __shared__ unsigned long long warr[16];
  __shared__ unsigned long long winS;
  __shared__ int lastblk;
  __shared__ unsigned topi[TOPK];
  __shared__ float topc[TOPK];
  const int tid = threadIdx.x;
  const unsigned i4 = blockIdx.x * 1024u + (unsigned)tid;
  const float s2 = 0.1f * sinf(beta[2]);

  // ---- mix2 ----
  float4 own = ((const float4*)A)[i4];
  tile[tid] = own;
  float4 gv[8];
  #pragma unroll
  for (int p = 19; p >= 12; --p) gv[19 - p] = ((const float4*)A)[i4 ^ (1u << (p - 2))];
  __syncthreads();

  float4 nb = make_float4(0.f, 0.f, 0.f, 0.f);
  #pragma unroll
  for (int u = 0; u < 8; ++u) {
    nb.x += gv[u].x; nb.y += gv[u].y; nb.z += gv[u].z; nb.w += gv[u].w;
  }
  #pragma unroll
  for (int p = 11; p >= 2; --p) {
    float4 v = tile[tid ^ (1 << (p - 2))];
    nb.x += v.x; nb.y += v.y; nb.z += v.z; nb.w += v.w;
  }
  nb.x += own.z; nb.y += own.w; nb.z += own.x; nb.w += own.y;
  nb.x += own.y; nb.y += own.x; nb.z += own.w; nb.w += own.z;

  const float prevscale = (float)(1.0 / sqrt(scal[1]));
  float4 m;
  m.x = prevscale * fmaf(s2, nb.x, own.x);
  m.y = prevscale * fmaf(s2, nb.y, own.y);
  m.z = prevscale * fmaf(s2, nb.z, own.z);
  m.w = prevscale * fmaf(s2, nb.w, own.w);

  double ss = (double)m.x * m.x + (double)m.y * m.y +
              (double)m.z * m.z + (double)m.w * m.w;
  #pragma unroll
  for (int off = 32; off > 0; off >>= 1) ss += __shfl_down(ss, off);
  if ((tid & 63) == 0) dpart[tid >> 6] = ss;
  __syncthreads();
  if (tid == 0) {
    double tt = 0.0;
    #pragma unroll
    for (int w = 0; w < 16; ++w) tt += dpart[w];
    atomicAdd(&scal[2], tt);
  }

  gbar(bars + 1);

  // ---- probs + keys ----
  const float scale = (float)(1.0 / sqrt(scal[2]));
  float4 pr;
  pr.x = m.x * scale; pr.x *= pr.x;
  pr.y = m.y * scale; pr.y *= pr.y;
  pr.z = m.z * scale; pr.z *= pr.z;
  pr.w = m.w * scale; pr.w *= pr.w;
  float* probs = out + 21;
  unsigned e0 = 4u * i4;
  probs[e0 + 0] = pr.x; probs[e0 + 1] = pr.y;
  probs[e0 + 2] = pr.z; probs[e0 + 3] = pr.w;

  unsigned long long k[4];
  k[0] = ((unsigned long long)__float_as_uint(pr.x) << 32) | (unsigned long long)(0xFFFFFFFFu - (e0 + 0));
  k[1] = ((unsigned long long)__float_as_uint(pr.y) << 32) | (unsigned long long)(0xFFFFFFFFu - (e0 + 1));
  k[2] = ((unsigned long long)__float_as_uint(pr.z) << 32) | (unsigned long long)(0xFFFFFFFFu - (e0 + 2));
  k[3] = ((unsigned long long)__float_as_uint(pr.w) << 32) | (unsigned long long)(0xFFFFFFFFu - (e0 + 3));

  for (int r = 0; r < TOPK; ++r) {
    unsigned long long loc = k[0];
    if (k[1] > loc) loc = k[1];
    if (k[2] > loc) loc = k[2];
    if (k[3] > loc) loc = k[3];
    #pragma unroll
    for (int off = 32; off > 0; off >>= 1) {
      unsigned long long o = __shfl_down(loc, off);
      if (o > loc) loc = o;
    }
    if ((tid & 63) == 0) warr[tid >> 6] = loc;
    __syncthreads();
    if (tid == 0) {
      unsigned long long win = warr[0];
      #pragma unroll
      for (int w = 1; w < 16; ++w) if (warr[w] > win) win = warr[w];
      winS = win;
      cand[blockIdx.x * TOPK + r] = win;
    }
    __syncthreads();
    unsigned long long win = winS;
    if (k[0] == win) k[0] = 0ull;
    if (k[1] == win) k[1] = 0ull;
    if (k[2] == win) k[2] = 0ull;
    if (k[3] == win) k[3] = 0ull;
    __syncthreads();
  }

  // ---- last-block ticket + merge + readout ----
  __threadfence();
  if (tid == 0) {
    unsigned old = atomicAdd(ctr, 1u);
    lastblk = (old == NBLK - 1) ? 1 : 0;
  }
  __syncthreads();
  if (!lastblk) return;
  __threadfence();

  unsigned long long c2[3] = {0ull, 0ull, 0ull};
  #pragma unroll
  for (int u = 0; u < 3; ++u) {
    int j = tid + 1024 * u;
    if (j < NCAND) c2[u] = cand[j];
  }
  for (int r = 0; r < TOPK; ++r) {
    unsigned long long loc = c2[0];
    if (c2[1] > loc) loc = c2[1];
    if (c2[2] > loc) loc = c2[2];
    #pragma unroll
    for (int off = 32; off > 0; off >>= 1) {
      unsigned long long o = __shfl_down(loc, off);
      if (o > loc) loc = o;
    }
    if ((tid & 63) == 0) warr[tid >> 6] = loc;
    __syncthreads();
    if (tid == 0) {
      unsigned long long win = warr[0];
      #pragma unroll
      for (int w = 1; w < 16; ++w) if (warr[w] > win) win = warr[w];
      winS = win;
      topi[r] = 0xFFFFFFFFu - (unsigned)(win & 0xFFFFFFFFull);
    }
    __syncthreads();
    unsigned long long win = winS;
    if (c2[0] == win) c2[0] = 0ull;
    if (c2[1] == win) c2[1] = 0ull;
    if (c2[2] == win) c2[2] = 0ull;
    __syncthreads();
  }

  const unsigned S = NSTATES;
  if (tid < TOPK * NV) {
    int kk = tid / NV, vv = tid % NV;
    out[21 + S + (unsigned)tid] = (float)((topi[kk] >> (NV - 1 - vv)) & 1u);
  }
  if (tid < TOPK) {
    float c = costs[topi[tid]];
    topc[tid] = c;
    out[21 + S + TOPK * NV + (unsigned)tid] = c;
  }
  __syncthreads();
  if (tid == 0) {
    int best = 0;
    for (int kk = 1; kk < TOPK; ++kk)
      if (topc[kk] < topc[best]) best = kk;
    unsigned gi = topi[best];
    for (int vv = 0; vv < NV; ++vv)
      out[vv] = (float)((gi >> (NV - 1 - vv)) & 1u);
    out[NV] = topc[best];
  }
}

// ===========================================================================
// Fallback: validated R10 mixer + ptop (used only if cooperative launch is
// rejected). Bitwise-identical outputs.
// ===========================================================================
template <int LAYER, bool ALIN, bool ALOUT>
__global__ __launch_bounds__(1024, 4) void k_mix(const float* __restrict__ pin,
                                                 const float* __restrict__ costs,
                                                 float* __restrict__ pout,
                                                 const float* __restrict__ gamma,
                                                 const float* __restrict__ beta,
                                                 double* __restrict__ scal) {
    __shared__ float4 tile[1024];
    __shared__ double dpart[16];
    const unsigned lq = threadIdx.x;
    const unsigned i4 = blockIdx.x * 1024u + lq;
    float s = 0.1f * sinf(beta[LAYER]);
    float prevscale = (LAYER == 0) ? 1.0f : (float)(1.0 / sqrt(scal[LAYER - 1]));
    auto ld4 = [&](unsigned j4) -> float4 {
        if (ALIN) return ((const float4*)pin)[j4];
        float4 a;
        a.x = pin[4u * j4 + 0]; a.y = pin[4u * j4 + 1];
        a.z = pin[4u * j4 + 2]; a.w = pin[4u * j4 + 3];
        return a;
    };
    float4 own = ld4(i4);
    tile[lq] = own;
    float4 gv[8];
    #pragma unroll
    for (int p = 19; p >= 12; --p) gv[19 - p] = ld4(i4 ^ (1u << (p - 2)));
    __syncthreads();
    float4 nb = make_float4(0.f, 0.f, 0.f, 0.f);
    #pragma unroll
    for (int u = 0; u < 8; ++u) { nb.x += gv[u].x; nb.y += gv[u].y; nb.z += gv[u].z; nb.w += gv[u].w; }
    #pragma unroll
    for (int p = 11; p >= 2; --p) {
        float4 v = tile[lq ^ (1u << (p - 2))];
        nb.x += v.x; nb.y += v.y; nb.z += v.z; nb.w += v.w;
    }
    nb.x += own.z; nb.y += own.w; nb.z += own.x; nb.w += own.y;
    nb.x += own.y; nb.y += own.x; nb.z += own.w; nb.w += own.z;
    float4 m;
    m.x = prevscale * fmaf(s, nb.x, own.x);
    m.y = prevscale * fmaf(s, nb.y, own.y);
    m.z = prevscale * fmaf(s, nb.z, own.z);
    m.w = prevscale * fmaf(s, nb.w, own.w);
    float4 o;
    if (LAYER < 2) {
        float gn = gamma[LAYER + 1];
        float4 c = ((const float4*)costs)[i4];
        o.x = m.x * cosf(gn * c.x); o.y = m.y * cosf(gn * c.y);
        o.z = m.z * cosf(gn * c.z); o.w = m.w * cosf(gn * c.w);
    } else o = m;
    if (ALOUT) ((float4*)pout)[i4] = o;
    else {
        pout[4u * i4 + 0] = o.x; pout[4u * i4 + 1] = o.y;
        pout[4u * i4 + 2] = o.z; pout[4u * i4 + 3] = o.w;
    }
    double ss = (double)m.x * m.x + (double)m.y * m.y + (double)m.z * m.z + (double)m.w * m.w;
    #pragma unroll
    for (int off = 32; off > 0; off >>= 1) ss += __shfl_down(ss, off);
    int wid = threadIdx.x >> 6;
    if ((threadIdx.x & 63) == 0) dpart[wid] = ss;
    __syncthreads();
    if (threadIdx.x == 0) {
        double tt = 0.0;
        #pragma unroll
        for (int w = 0; w < 16; ++w) tt += dpart[w];
        atomicAdd(&scal[LAYER], tt);
    }
}

template <bool ALIN>
__global__ __launch_bounds__(256) void k_ptop(const float* __restrict__ A,
                                              const double* __restrict__ scal2,
                                              const float* __restrict__ costs,
                                              float* __restrict__ out,
                                              unsigned long long* __restrict__ cand,
                                              unsigned* __restrict__ ctr) {
    __shared__ unsigned long long warr[4];
    __shared__ int lastblk;
    __shared__ unsigned topi[TOPK];
    __shared__ float topc[TOPK];
    const int tid = threadIdx.x;
    float* probs_out = out + 21;
    unsigned b4 = blockIdx.x * 1024u;
    float scale = (float)(1.0 / sqrt(*scal2));
    unsigned long long k[16];
    #pragma unroll
    for (int u = 0; u < 4; ++u) {
        unsigned j4 = b4 + (unsigned)tid + 256u * u;
        float4 v;
        if (ALIN) v = ((const float4*)A)[j4];
        else {
            v.x = A[4u * j4 + 0]; v.y = A[4u * j4 + 1];
            v.z = A[4u * j4 + 2]; v.w = A[4u * j4 + 3];
        }
        float4 p;
        p.x = v.x * scale; p.x *= p.x;
        p.y = v.y * scale; p.y *= p.y;
        p.z = v.z * scale; p.z *= p.z;
        p.w = v.w * scale; p.w *= p.w;
        unsigned e0 = 4u * j4;
        probs_out[e0 + 0] = p.x; probs_out[e0 + 1] = p.y;
        probs_out[e0 + 2] = p.z; probs_out[e0 + 3] = p.w;
        k[4 * u + 0] = ((unsigned long long)__float_as_uint(p.x) << 32) | (unsigned long long)(0xFFFFFFFFu - (e0 + 0));
        k[4 * u + 1] = ((unsigned long long)__float_as_uint(p.y) << 32) | (unsigned long long)(0xFFFFFFFFu - (e0 + 1));
        k[4 * u + 2] = ((unsigned long long)__float_as_uint(p.z) << 32) | (unsigned long long)(0xFFFFFFFFu - (e0 + 2));
        k[4 * u + 3] = ((unsigned long long)__float_as_uint(p.w) << 32) | (unsigned long long)(0xFFFFFFFFu - (e0 + 3));
    }
    for (int r = 0; r < TOPK; ++r) {
        unsigned long long loc = 0ull;
        #pragma unroll
        for (int j = 0; j < 16; ++j) if (k[j] > loc) loc = k[j];
        #pragma unroll
        for (int off = 32; off > 0; off >>= 1) {
            unsigned long long o = __shfl_down(loc, off);
            if (o > loc) loc = o;
        }
        if ((tid & 63) == 0) warr[tid >> 6] = loc;
        __syncthreads();
        unsigned long long win = warr[0];
        if (warr[1] > win) win = warr[1];
        if (warr[2] > win) win = warr[2];
        if (warr[3] > win) win = warr[3];
        __syncthreads();
        #pragma unroll
        for (int j = 0; j < 16; ++j) if (k[j] == win) k[j] = 0ull;
        if (tid == 0) cand[blockIdx.x * TOPK + r] = win;
    }
    __threadfence();
    if (tid == 0) {
        unsigned old = atomicAdd(ctr, 1u);
        lastblk = (old == NB1 - 1) ? 1 : 0;
    }
    __syncthreads();
    if (!lastblk) return;
    __threadfence();
    unsigned long long c2[TOPK];
    #pragma unroll
    for (int u = 0; u < TOPK; ++u) c2[u] = cand[tid + 256 * u];
    for (int r = 0; r < TOPK; ++r) {
        unsigned long long loc = 0ull;
        #pragma unroll
        for (int u = 0; u < TOPK; ++u) if (c2[u] > loc) loc = c2[u];
        #pragma unroll
        for (int off = 32; off > 0; off >>= 1) {
            unsigned long long o = __shfl_down(loc, off);
            if (o > loc) loc = o;
        }
        if ((tid & 63) == 0) warr[tid >> 6] = loc;
        __syncthreads();
        unsigned long long win = warr[0];
        if (warr[1] > win) win = warr[1];
        if (warr[2] > win) win = warr[2];
        if (warr[3] > win) win = warr[3];
        __syncthreads();
        #pragma unroll
        for (int u = 0; u < TOPK; ++u) if (c2[u] == win) c2[u] = 0ull;
        if (tid == 0) topi[r] = 0xFFFFFFFFu - (unsigned)(win & 0xFFFFFFFFull);
        __syncthreads();
    }
    const unsigned S = NSTATES;
    if (tid < TOPK * NV) {
        int kk = tid / NV, vv = tid % NV;
        out[21 + S + (unsigned)tid] = (float)((topi[kk] >> (NV - 1 - vv)) & 1u);
    }
    if (tid < TOPK) {
        float c = costs[topi[tid]];
        topc[tid] = c;
        out[21 + S + TOPK * NV + (unsigned)tid] = c;
    }
    __syncthreads();
    if (tid == 0) {
        int best = 0;
        for (int kk = 1; kk < TOPK; ++kk)
            if (topc[kk] < topc[best]) best = kk;
        unsigned gi = topi[best];
        for (int vv = 0; vv < NV; ++vv)
            out[vv] = (float)((gi >> (NV - 1 - vv)) & 1u);
        out[NV] = topc[best];
    }
}

extern "C" void kernel_launch(void* const* d_in, const int* in_sizes, int n_in,
                              void* d_out_, int out_size, void* d_ws, size_t ws_size,
                              hipStream_t stream) {
    (void)in_sizes; (void)n_in; (void)out_size;
    const float* C     = (const float*)d_in[0];
    const float* beta  = (const float*)d_in[1];
    const float* gamma = (const float*)d_in[2];
    float* out = (float*)d_out_;
    char* ws = (char*)d_ws;
    const size_t S4 = (size_t)NSTATES * sizeof(float);

    double* scal = (double*)ws;                                   // 8 doubles
    unsigned* ctr = (unsigned*)(ws + 64);
    unsigned* bars = (unsigned*)(ws + 128);                       // 2 counters
    unsigned long long* cand = (unsigned long long*)(ws + 1024);  // 20 KB
    float* costs = (float*)(ws + 32768);
    float* A     = (float*)(ws + 32768 + S4);                     // ph0 / pm2
    const size_t need_full = 32768 + 3 * S4;
    bool wsbig = (ws_size >= need_full);
    float* B = wsbig ? (float*)(ws + 32768 + 2 * S4) : (out + 21); // pm1

    // zero scal/ctr/barrier counters each call (inside the graph)
    hipMemsetAsync(ws, 0, 256, stream);

    // K1: costs + ph0
    k_costs<<<256, 512, 0, stream>>>(C, costs, A, gamma, scal, ctr);

    // K2: fused mix0+mix1 (cooperative, 1 internal barrier)
    hipError_t err;
    {
        void* args[] = {(void*)&A, (void*)&costs, (void*)&B, (void*)&gamma,
                        (void*)&beta, (void*)&scal, (void*)&bars};
        const void* fn = wsbig ? (const void*)k_mix01<true> : (const void*)k_mix01<false>;
        err = hipLaunchCooperativeKernel(fn, dim3(NBLK), dim3(1024), args, 0, stream);
    }
    if (err == hipSuccess) {
        // K3: fused mix2 + probs + top-k (cooperative, 1 barrier + ticket)
        void* args[] = {(void*)&A, (void*)&costs, (void*)&beta, (void*)&out,
                        (void*)&scal, (void*)&cand, (void*)&bars, (void*)&ctr};
        err = hipLaunchCooperativeKernel((const void*)k_mix2top, dim3(NBLK),
                                         dim3(1024), args, 0, stream);
        if (err == hipSuccess) return;
        // K3 rejected: finish with fallback mix2 + ptop (A holds pm2)
        if (wsbig) {
            k_mix<2, true, true ><<<256, 1024, 0, stream>>>(A, costs, B, gamma, beta, scal);
            k_ptop<true ><<<NB1, 256, 0, stream>>>(B, scal + 2, costs, out, cand, ctr);
        } else {
            k_mix<2, true, false><<<256, 1024, 0, stream>>>(A, costs, B, gamma, beta, scal);
            k_ptop<false><<<NB1, 256, 0, stream>>>(B, scal + 2, costs, out, cand, ctr);
        }
        return;
    }

    // Full fallback: validated R10 mixer chain
    if (wsbig) {
        k_mix<0, true, true ><<<256, 1024, 0, stream>>>(A, costs, B, gamma, beta, scal);
        k_mix<1, true, true ><<<256, 1024, 0, stream>>>(B, costs, A, gamma, beta, scal);
        k_mix<2, true, true ><<<256, 1024, 0, stream>>>(A, costs, B, gamma, beta, scal);
        k_ptop<true ><<<NB1, 256, 0, stream>>>(B, scal + 2, costs, out, cand, ctr);
    } else {
        k_mix<0, true, false><<<256, 1024, 0, stream>>>(A, costs, B, gamma, beta, scal);
        k_mix<1, false, true><<<256, 1024, 0, stream>>>(B, costs, A, gamma, beta, scal);
        k_mix<2, true, false><<<256, 1024, 0, stream>>>(A, costs, B, gamma, beta, scal);
        k_ptop<false><<<NB1, 256, 0, stream>>>(B, scal + 2, costs, out, cand, ctr);
    }
}

// Round 12
// 112.644 us; speedup vs baseline: 1.9197x; 1.9197x over previous
//
#include <hip/hip_runtime.h>
#include <math.h>

#define NV 20
#define NC 64
#define NSTATES (1u << 20)
#define TOPK 10
#define NB1 256              // ptop blocks
#define NCAND (NB1 * TOPK)   // 2560

// ---------------------------------------------------------------------------
// K1: costs + ph0 (validated chunked numerics; zeroes scal/ctr).
// 256 blocks x 512 threads, 8 states/thread.
// ---------------------------------------------------------------------------
__global__ __launch_bounds__(512) void k_costs(const float* __restrict__ C,
                                               float* __restrict__ costs,
                                               float* __restrict__ ph0,
                                               const float* __restrict__ gamma,
                                               double* __restrict__ scal,
                                               unsigned* __restrict__ ctr) {
    __shared__ float CT[17][NC];    // CT[k][c] = C[c][16-k]
    __shared__ float lowT[8][NC];   // low 3 bits (cols 19,18,17)
    const int tid = threadIdx.x;

    if (blockIdx.x == 0) {
        if (tid < 8) scal[tid] = 0.0;
        if (tid == 8) *ctr = 0u;
    }

    for (int e = tid; e < 17 * NC; e += 512) {
        int k = e / NC, c = e % NC;
        CT[k][c] = C[c * NV + (16 - k)];
    }
    for (int e = tid; e < 8 * NC; e += 512) {
        int m = e >> 6, c = e & 63;
        float v = 0.0f;
        if (m & 1) v += C[c * NV + 19];
        if (m & 2) v += C[c * NV + 18];
        if (m & 4) v += C[c * NV + 17];
        lowT[m][c] = v;
    }
    __syncthreads();

    unsigned t = blockIdx.x * 512u + (unsigned)tid;   // < 2^17, 8 states each
    float g0 = gamma[0];

    float cost[8];
    #pragma unroll
    for (int s = 0; s < 8; ++s)
        cost[s] = 0.1f * (float)__popc(t * 8u + (unsigned)s);

    #pragma unroll
    for (int cc = 0; cc < 4; ++cc) {       // 16 constraints per chunk
        float4 bb[4];
        #pragma unroll
        for (int q = 0; q < 4; ++q) bb[q] = make_float4(-1.f, -1.f, -1.f, -1.f);
        #pragma unroll
        for (int k = 0; k < 17; ++k) {     // i-bit (k+3) == t-bit k
            float bf = (float)((t >> k) & 1u);
            const float4* row = ((const float4*)(&CT[k][0])) + 4 * cc;
            #pragma unroll
            for (int q = 0; q < 4; ++q) {
                float4 cv = row[q];
                bb[q].x = fmaf(bf, cv.x, bb[q].x);
                bb[q].y = fmaf(bf, cv.y, bb[q].y);
                bb[q].z = fmaf(bf, cv.z, bb[q].z);
                bb[q].w = fmaf(bf, cv.w, bb[q].w);
            }
        }
        #pragma unroll
        for (int s = 0; s < 8; ++s) {
            const float4* lrow = ((const float4*)(&lowT[s][0])) + 4 * cc;
            #pragma unroll
            for (int q = 0; q < 4; ++q) {
                float4 lv = lrow[q];
                float4 v;
                v.x = bb[q].x + lv.x; v.y = bb[q].y + lv.y;
                v.z = bb[q].z + lv.z; v.w = bb[q].w + lv.w;
                float r;
                r = fmaxf(v.x, 0.f); cost[s] = fmaf(r, r, cost[s]);
                r = fmaxf(v.y, 0.f); cost[s] = fmaf(r, r, cost[s]);
                r = fmaxf(v.z, 0.f); cost[s] = fmaf(r, r, cost[s]);
                r = fmaxf(v.w, 0.f); cost[s] = fmaf(r, r, cost[s]);
            }
        }
    }

    float4* co = (float4*)(costs + (size_t)t * 8u);
    co[0] = make_float4(cost[0], cost[1], cost[2], cost[3]);
    co[1] = make_float4(cost[4], cost[5], cost[6], cost[7]);
    float ph[8];
    #pragma unroll
    for (int s = 0; s < 8; ++s) ph[s] = 0x1p-10f * cosf(g0 * cost[s]);
    float4* po = (float4*)(ph0 + (size_t)t * 8u);
    po[0] = make_float4(ph[0], ph[1], ph[2], ph[3]);
    po[1] = make_float4(ph[4], ph[5], ph[6], ph[7]);
}

// ---------------------------------------------------------------------------
// Mixer over pre-phased pin. REGRIDDED for latency: 1024 blocks x 256 threads
// (4 blocks/CU -> 4 independent barrier groups, ~11 loads in flight/thread).
// 4 KB LDS tile covers flips p=2..9; far gathers p=19..10 (10 passes);
// p=1,0 in-quad swizzles. Addend order p=19..0 descending — bitwise identical
// to the validated R4/R10 mixers (absmax 2.98e-8).
//   m[i]  = prevscale * (pin[i] + s*sum_{p=19..0} pin[i^(1<<p)])
//   LAYER<2: pout = m*cos(gamma[L+1]*costs);  LAYER==2: pout = m
// ---------------------------------------------------------------------------
template <int LAYER, bool ALIN, bool ALOUT>
__global__ __launch_bounds__(256) void k_mix(const float* __restrict__ pin,
                                             const float* __restrict__ costs,
                                             float* __restrict__ pout,
                                             const float* __restrict__ gamma,
                                             const float* __restrict__ beta,
                                             double* __restrict__ scal) {
    __shared__ float4 tile[256];      // 4 KB
    __shared__ double dpart[4];
    const unsigned lq = threadIdx.x;               // local quad 0..255
    const unsigned i4 = blockIdx.x * 256u + lq;    // global quad < 2^18
    float s = 0.1f * sinf(beta[LAYER]);
    float prevscale = (LAYER == 0) ? 1.0f : (float)(1.0 / sqrt(scal[LAYER - 1]));

    auto ld4 = [&](unsigned j4) -> float4 {
        if (ALIN) return ((const float4*)pin)[j4];
        float4 a;
        a.x = pin[4u * j4 + 0]; a.y = pin[4u * j4 + 1];
        a.z = pin[4u * j4 + 2]; a.w = pin[4u * j4 + 3];
        return a;
    };

    float4 own = ld4(i4);
    tile[lq] = own;

    // 10 far gathers (p = 19..10), one batch for max memory-level parallelism
    float4 gv[10];
    #pragma unroll
    for (int p = 19; p >= 10; --p) gv[19 - p] = ld4(i4 ^ (1u << (p - 2)));

    __syncthreads();

    float4 nb = make_float4(0.f, 0.f, 0.f, 0.f);
    #pragma unroll
    for (int u = 0; u < 10; ++u) {     // p = 19..10 descending
        nb.x += gv[u].x; nb.y += gv[u].y; nb.z += gv[u].z; nb.w += gv[u].w;
    }
    #pragma unroll
    for (int p = 9; p >= 2; --p) {     // local flips from LDS (lq ^ <=128)
        float4 v = tile[lq ^ (1u << (p - 2))];
        nb.x += v.x; nb.y += v.y; nb.z += v.z; nb.w += v.w;
    }
    // p = 1: element e gets own element e^2
    nb.x += own.z; nb.y += own.w; nb.z += own.x; nb.w += own.y;
    // p = 0: element e gets own element e^1
    nb.x += own.y; nb.y += own.x; nb.z += own.w; nb.w += own.z;

    float4 m;
    m.x = prevscale * fmaf(s, nb.x, own.x);
    m.y = prevscale * fmaf(s, nb.y, own.y);
    m.z = prevscale * fmaf(s, nb.z, own.z);
    m.w = prevscale * fmaf(s, nb.w, own.w);

    float4 o;
    if (LAYER < 2) {
        float gn = gamma[LAYER + 1];
        float4 c = ((const float4*)costs)[i4];
        o.x = m.x * cosf(gn * c.x);
        o.y = m.y * cosf(gn * c.y);
        o.z = m.z * cosf(gn * c.z);
        o.w = m.w * cosf(gn * c.w);
    } else {
        o = m;
    }
    if (ALOUT) {
        ((float4*)pout)[i4] = o;
    } else {
        pout[4u * i4 + 0] = o.x; pout[4u * i4 + 1] = o.y;
        pout[4u * i4 + 2] = o.z; pout[4u * i4 + 3] = o.w;
    }

    double ss = (double)m.x * m.x + (double)m.y * m.y +
                (double)m.z * m.z + (double)m.w * m.w;
    #pragma unroll
    for (int off = 32; off > 0; off >>= 1) ss += __shfl_down(ss, off);
    int wid = threadIdx.x >> 6;
    if ((threadIdx.x & 63) == 0) dpart[wid] = ss;
    __syncthreads();
    if (threadIdx.x == 0)
        atomicAdd(&scal[LAYER], dpart[0] + dpart[1] + dpart[2] + dpart[3]);
}

// ---------------------------------------------------------------------------
// Fused probs + top-k stage 1 + (last block) stage 2 merge & readout.
// Identical to the validated R4/R10 version.
// ---------------------------------------------------------------------------
template <bool ALIN>
__global__ __launch_bounds__(256) void k_ptop(const float* __restrict__ A,
                                              const double* __restrict__ scal2,
                                              const float* __restrict__ costs,
                                              float* __restrict__ out,
                                              unsigned long long* __restrict__ cand,
                                              unsigned* __restrict__ ctr) {
    __shared__ unsigned long long warr[4];
    __shared__ int lastblk;
    __shared__ unsigned topi[TOPK];
    __shared__ float topc[TOPK];
    const int tid = threadIdx.x;
    float* probs_out = out + 21;
    unsigned b4 = blockIdx.x * 1024u;   // float4 base
    float scale = (float)(1.0 / sqrt(*scal2));

    unsigned long long k[16];
    #pragma unroll
    for (int u = 0; u < 4; ++u) {
        unsigned j4 = b4 + (unsigned)tid + 256u * u;
        float4 v;
        if (ALIN) v = ((const float4*)A)[j4];
        else {
            v.x = A[4u * j4 + 0]; v.y = A[4u * j4 + 1];
            v.z = A[4u * j4 + 2]; v.w = A[4u * j4 + 3];
        }
        float4 p;
        p.x = v.x * scale; p.x *= p.x;
        p.y = v.y * scale; p.y *= p.y;
        p.z = v.z * scale; p.z *= p.z;
        p.w = v.w * scale; p.w *= p.w;
        unsigned e0 = 4u * j4;
        probs_out[e0 + 0] = p.x; probs_out[e0 + 1] = p.y;
        probs_out[e0 + 2] = p.z; probs_out[e0 + 3] = p.w;
        k[4 * u + 0] = ((unsigned long long)__float_as_uint(p.x) << 32) | (unsigned long long)(0xFFFFFFFFu - (e0 + 0));
        k[4 * u + 1] = ((unsigned long long)__float_as_uint(p.y) << 32) | (unsigned long long)(0xFFFFFFFFu - (e0 + 1));
        k[4 * u + 2] = ((unsigned long long)__float_as_uint(p.z) << 32) | (unsigned long long)(0xFFFFFFFFu - (e0 + 2));
        k[4 * u + 3] = ((unsigned long long)__float_as_uint(p.w) << 32) | (unsigned long long)(0xFFFFFFFFu - (e0 + 3));
    }

    for (int r = 0; r < TOPK; ++r) {
        unsigned long long loc = 0ull;
        #pragma unroll
        for (int j = 0; j < 16; ++j) if (k[j] > loc) loc = k[j];
        #pragma unroll
        for (int off = 32; off > 0; off >>= 1) {
            unsigned long long o = __shfl_down(loc, off);
            if (o > loc) loc = o;
        }
        if ((tid & 63) == 0) warr[tid >> 6] = loc;
        __syncthreads();
        unsigned long long win = warr[0];
        if (warr[1] > win) win = warr[1];
        if (warr[2] > win) win = warr[2];
        if (warr[3] > win) win = warr[3];
        __syncthreads();
        #pragma unroll
        for (int j = 0; j < 16; ++j) if (k[j] == win) k[j] = 0ull;
        if (tid == 0) cand[blockIdx.x * TOPK + r] = win;
    }

    // ---- last-block ticket ----
    __threadfence();
    if (tid == 0) {
        unsigned old = atomicAdd(ctr, 1u);
        lastblk = (old == NB1 - 1) ? 1 : 0;
    }
    __syncthreads();
    if (!lastblk) return;
    __threadfence();

    // ---- stage 2: merge NCAND candidates with this one block ----
    unsigned long long c2[TOPK];
    #pragma unroll
    for (int u = 0; u < TOPK; ++u) c2[u] = cand[tid + 256 * u];

    for (int r = 0; r < TOPK; ++r) {
        unsigned long long loc = 0ull;
        #pragma unroll
        for (int u = 0; u < TOPK; ++u) if (c2[u] > loc) loc = c2[u];
        #pragma unroll
        for (int off = 32; off > 0; off >>= 1) {
            unsigned long long o = __shfl_down(loc, off);
            if (o > loc) loc = o;
        }
        if ((tid & 63) == 0) warr[tid >> 6] = loc;
        __syncthreads();
        unsigned long long win = warr[0];
        if (warr[1] > win) win = warr[1];
        if (warr[2] > win) win = warr[2];
        if (warr[3] > win) win = warr[3];
        __syncthreads();
        #pragma unroll
        for (int u = 0; u < TOPK; ++u) if (c2[u] == win) c2[u] = 0ull;
        if (tid == 0) topi[r] = 0xFFFFFFFFu - (unsigned)(win & 0xFFFFFFFFull);
        __syncthreads();
    }

    const unsigned S = NSTATES;
    if (tid < TOPK * NV) {
        int kk = tid / NV, vv = tid % NV;
        out[21 + S + (unsigned)tid] = (float)((topi[kk] >> (NV - 1 - vv)) & 1u);
    }
    if (tid < TOPK) {
        float c = costs[topi[tid]];
        topc[tid] = c;
        out[21 + S + TOPK * NV + (unsigned)tid] = c;
    }
    __syncthreads();
    if (tid == 0) {
        int best = 0;
        for (int kk = 1; kk < TOPK; ++kk)
            if (topc[kk] < topc[best]) best = kk;
        unsigned gi = topi[best];
        for (int vv = 0; vv < NV; ++vv)
            out[vv] = (float)((gi >> (NV - 1 - vv)) & 1u);
        out[NV] = topc[best];
    }
}

extern "C" void kernel_launch(void* const* d_in, const int* in_sizes, int n_in,
                              void* d_out_, int out_size, void* d_ws, size_t ws_size,
                              hipStream_t stream) {
    (void)in_sizes; (void)n_in; (void)out_size;
    const float* C     = (const float*)d_in[0];
    const float* beta  = (const float*)d_in[1];
    const float* gamma = (const float*)d_in[2];
    float* out = (float*)d_out_;
    char* ws = (char*)d_ws;
    const size_t S4 = (size_t)NSTATES * sizeof(float);

    double* scal = (double*)ws;                                   // 8 doubles
    unsigned* ctr = (unsigned*)(ws + 64);
    unsigned long long* cand = (unsigned long long*)(ws + 1024);  // 20 KB
    float* costs = (float*)(ws + 32768);
    float* A     = (float*)(ws + 32768 + S4);                     // ph0 / pm2
    const size_t need_full = 32768 + 3 * S4;
    bool wsbig = (ws_size >= need_full);
    float* B = wsbig ? (float*)(ws + 32768 + 2 * S4) : (out + 21); // pm1 / m2

    // costs + layer-0 phase array (A = ph0)
    k_costs<<<256, 512, 0, stream>>>(C, costs, A, gamma, scal, ctr);

    // mix0: A(ph0) -> B(pm1);  mix1: B(pm1) -> A(pm2);  mix2: A(pm2) -> B(m2)
    if (wsbig) {
        k_mix<0, true, true ><<<1024, 256, 0, stream>>>(A, costs, B, gamma, beta, scal);
        k_mix<1, true, true ><<<1024, 256, 0, stream>>>(B, costs, A, gamma, beta, scal);
        k_mix<2, true, true ><<<1024, 256, 0, stream>>>(A, costs, B, gamma, beta, scal);
        k_ptop<true ><<<NB1, 256, 0, stream>>>(B, scal + 2, costs, out, cand, ctr);
    } else {
        k_mix<0, true, false><<<1024, 256, 0, stream>>>(A, costs, B, gamma, beta, scal);
        k_mix<1, false, true><<<1024, 256, 0, stream>>>(B, costs, A, gamma, beta, scal);
        k_mix<2, true, false><<<1024, 256, 0, stream>>>(A, costs, B, gamma, beta, scal);
        k_ptop<false><<<NB1, 256, 0, stream>>>(B, scal + 2, costs, out, cand, ctr);
    }
}

// Round 13
// 84.606 us; speedup vs baseline: 2.5559x; 1.3314x over previous
//
#include <hip/hip_runtime.h>
#include <hip/hip_fp16.h>
#include <math.h>

#define NV 20
#define NC 64
#define NSTATES (1u << 20)
#define TOPK 10
#define NB1 256              // ptop blocks
#define NCAND (NB1 * TOPK)   // 2560

struct h4 { __half2 lo, hi; };   // 4 halves = one quad, 8 B

// ---------------------------------------------------------------------------
// K1: costs + ph0 (f32) [+ ph0 in fp16 for the mixers' far gathers].
// Validated chunked numerics (absmax 2.98e-8 in f32 pipeline); zeroes scal/ctr.
// 256 blocks x 512 threads, 8 states/thread.
// ---------------------------------------------------------------------------
template <bool WRITEH>
__global__ __launch_bounds__(512) void k_costs(const float* __restrict__ C,
                                               float* __restrict__ costs,
                                               float* __restrict__ ph0,
                                               h4* __restrict__ ph0h,
                                               const float* __restrict__ gamma,
                                               double* __restrict__ scal,
                                               unsigned* __restrict__ ctr) {
    __shared__ float CT[17][NC];    // CT[k][c] = C[c][16-k]
    __shared__ float lowT[8][NC];   // low 3 bits (cols 19,18,17)
    const int tid = threadIdx.x;

    if (blockIdx.x == 0) {
        if (tid < 8) scal[tid] = 0.0;
        if (tid == 8) *ctr = 0u;
    }

    for (int e = tid; e < 17 * NC; e += 512) {
        int k = e / NC, c = e % NC;
        CT[k][c] = C[c * NV + (16 - k)];
    }
    for (int e = tid; e < 8 * NC; e += 512) {
        int m = e >> 6, c = e & 63;
        float v = 0.0f;
        if (m & 1) v += C[c * NV + 19];
        if (m & 2) v += C[c * NV + 18];
        if (m & 4) v += C[c * NV + 17];
        lowT[m][c] = v;
    }
    __syncthreads();

    unsigned t = blockIdx.x * 512u + (unsigned)tid;   // < 2^17, 8 states each
    float g0 = gamma[0];

    float cost[8];
    #pragma unroll
    for (int s = 0; s < 8; ++s)
        cost[s] = 0.1f * (float)__popc(t * 8u + (unsigned)s);

    #pragma unroll
    for (int cc = 0; cc < 4; ++cc) {       // 16 constraints per chunk
        float4 bb[4];
        #pragma unroll
        for (int q = 0; q < 4; ++q) bb[q] = make_float4(-1.f, -1.f, -1.f, -1.f);
        #pragma unroll
        for (int k = 0; k < 17; ++k) {     // i-bit (k+3) == t-bit k
            float bf = (float)((t >> k) & 1u);
            const float4* row = ((const float4*)(&CT[k][0])) + 4 * cc;
            #pragma unroll
            for (int q = 0; q < 4; ++q) {
                float4 cv = row[q];
                bb[q].x = fmaf(bf, cv.x, bb[q].x);
                bb[q].y = fmaf(bf, cv.y, bb[q].y);
                bb[q].z = fmaf(bf, cv.z, bb[q].z);
                bb[q].w = fmaf(bf, cv.w, bb[q].w);
            }
        }
        #pragma unroll
        for (int s = 0; s < 8; ++s) {
            const float4* lrow = ((const float4*)(&lowT[s][0])) + 4 * cc;
            #pragma unroll
            for (int q = 0; q < 4; ++q) {
                float4 lv = lrow[q];
                float4 v;
                v.x = bb[q].x + lv.x; v.y = bb[q].y + lv.y;
                v.z = bb[q].z + lv.z; v.w = bb[q].w + lv.w;
                float r;
                r = fmaxf(v.x, 0.f); cost[s] = fmaf(r, r, cost[s]);
                r = fmaxf(v.y, 0.f); cost[s] = fmaf(r, r, cost[s]);
                r = fmaxf(v.z, 0.f); cost[s] = fmaf(r, r, cost[s]);
                r = fmaxf(v.w, 0.f); cost[s] = fmaf(r, r, cost[s]);
            }
        }
    }

    float4* co = (float4*)(costs + (size_t)t * 8u);
    co[0] = make_float4(cost[0], cost[1], cost[2], cost[3]);
    co[1] = make_float4(cost[4], cost[5], cost[6], cost[7]);
    float ph[8];
    #pragma unroll
    for (int s = 0; s < 8; ++s) ph[s] = 0x1p-10f * cosf(g0 * cost[s]);
    float4* po = (float4*)(ph0 + (size_t)t * 8u);
    po[0] = make_float4(ph[0], ph[1], ph[2], ph[3]);
    po[1] = make_float4(ph[4], ph[5], ph[6], ph[7]);
    if (WRITEH) {
        h4 h0, h1;
        h0.lo = __floats2half2_rn(ph[0], ph[1]);
        h0.hi = __floats2half2_rn(ph[2], ph[3]);
        h1.lo = __floats2half2_rn(ph[4], ph[5]);
        h1.hi = __floats2half2_rn(ph[6], ph[7]);
        ph0h[(size_t)t * 2u + 0] = h0;
        ph0h[(size_t)t * 2u + 1] = h1;
    }
}

// ---------------------------------------------------------------------------
// Hybrid mixer (R4/R10 structure, validated): own tile + LDS flips + costs in
// f32 (exact); only the 8 FAR gathers (p=19..12) read the fp16 shadow array
// (half the gather bytes). Addition order p=19..0 descending unchanged.
//   m[i]  = prevscale * (pin[i] + s*sum_{p=19..0} pin[i^(1<<p)])
//   LAYER<2: pout = m*cos(gamma[L+1]*costs), pouth = fp16(pout)
//   LAYER==2: pout = m (no half output)
// ---------------------------------------------------------------------------
template <int LAYER>
__global__ __launch_bounds__(1024, 4) void k_mixh(const float* __restrict__ pin,
                                                  const h4* __restrict__ pinh,
                                                  const float* __restrict__ costs,
                                                  float* __restrict__ pout,
                                                  h4* __restrict__ pouth,
                                                  const float* __restrict__ gamma,
                                                  const float* __restrict__ beta,
                                                  double* __restrict__ scal) {
    __shared__ float4 tile[1024];     // 16 KB (f32, exact)
    __shared__ double dpart[16];
    const unsigned lq = threadIdx.x;
    const unsigned i4 = blockIdx.x * 1024u + lq;
    float s = 0.1f * sinf(beta[LAYER]);
    float prevscale = (LAYER == 0) ? 1.0f : (float)(1.0 / sqrt(scal[LAYER - 1]));

    float4 own = ((const float4*)pin)[i4];
    tile[lq] = own;

    // 8 far gathers from the fp16 shadow (16 bytes -> 8 bytes per quad)
    h4 gv[8];
    #pragma unroll
    for (int p = 19; p >= 12; --p) gv[19 - p] = pinh[i4 ^ (1u << (p - 2))];

    __syncthreads();

    float4 nb = make_float4(0.f, 0.f, 0.f, 0.f);
    #pragma unroll
    for (int u = 0; u < 8; ++u) {      // p = 19..12 descending
        float2 f0 = __half22float2(gv[u].lo);
        float2 f1 = __half22float2(gv[u].hi);
        nb.x += f0.x; nb.y += f0.y; nb.z += f1.x; nb.w += f1.y;
    }
    #pragma unroll
    for (int p = 11; p >= 2; --p) {    // local flips from LDS (f32 exact)
        float4 v = tile[lq ^ (1u << (p - 2))];
        nb.x += v.x; nb.y += v.y; nb.z += v.z; nb.w += v.w;
    }
    // p = 1: element e gets own element e^2
    nb.x += own.z; nb.y += own.w; nb.z += own.x; nb.w += own.y;
    // p = 0: element e gets own element e^1
    nb.x += own.y; nb.y += own.x; nb.z += own.w; nb.w += own.z;

    float4 m;
    m.x = prevscale * fmaf(s, nb.x, own.x);
    m.y = prevscale * fmaf(s, nb.y, own.y);
    m.z = prevscale * fmaf(s, nb.z, own.z);
    m.w = prevscale * fmaf(s, nb.w, own.w);

    float4 o;
    if (LAYER < 2) {
        float gn = gamma[LAYER + 1];
        float4 c = ((const float4*)costs)[i4];
        o.x = m.x * cosf(gn * c.x);
        o.y = m.y * cosf(gn * c.y);
        o.z = m.z * cosf(gn * c.z);
        o.w = m.w * cosf(gn * c.w);
    } else {
        o = m;
    }
    ((float4*)pout)[i4] = o;
    if (LAYER < 2) {
        h4 oh;
        oh.lo = __floats2half2_rn(o.x, o.y);
        oh.hi = __floats2half2_rn(o.z, o.w);
        pouth[i4] = oh;
    }

    double ss = (double)m.x * m.x + (double)m.y * m.y +
                (double)m.z * m.z + (double)m.w * m.w;
    #pragma unroll
    for (int off = 32; off > 0; off >>= 1) ss += __shfl_down(ss, off);
    int wid = threadIdx.x >> 6;
    if ((threadIdx.x & 63) == 0) dpart[wid] = ss;
    __syncthreads();
    if (threadIdx.x == 0) {
        double tt = 0.0;
        #pragma unroll
        for (int w = 0; w < 16; ++w) tt += dpart[w];
        atomicAdd(&scal[LAYER], tt);
    }
}

// ---------------------------------------------------------------------------
// Fallback f32 mixer (R10, validated) for the small-workspace path.
// ---------------------------------------------------------------------------
template <int LAYER, bool ALIN, bool ALOUT>
__global__ __launch_bounds__(1024, 4) void k_mix(const float* __restrict__ pin,
                                                 const float* __restrict__ costs,
                                                 float* __restrict__ pout,
                                                 const float* __restrict__ gamma,
                                                 const float* __restrict__ beta,
                                                 double* __restrict__ scal) {
    __shared__ float4 tile[1024];
    __shared__ double dpart[16];
    const unsigned lq = threadIdx.x;
    const unsigned i4 = blockIdx.x * 1024u + lq;
    float s = 0.1f * sinf(beta[LAYER]);
    float prevscale = (LAYER == 0) ? 1.0f : (float)(1.0 / sqrt(scal[LAYER - 1]));
    auto ld4 = [&](unsigned j4) -> float4 {
        if (ALIN) return ((const float4*)pin)[j4];
        float4 a;
        a.x = pin[4u * j4 + 0]; a.y = pin[4u * j4 + 1];
        a.z = pin[4u * j4 + 2]; a.w = pin[4u * j4 + 3];
        return a;
    };
    float4 own = ld4(i4);
    tile[lq] = own;
    float4 gv[8];
    #pragma unroll
    for (int p = 19; p >= 12; --p) gv[19 - p] = ld4(i4 ^ (1u << (p - 2)));
    __syncthreads();
    float4 nb = make_float4(0.f, 0.f, 0.f, 0.f);
    #pragma unroll
    for (int u = 0; u < 8; ++u) { nb.x += gv[u].x; nb.y += gv[u].y; nb.z += gv[u].z; nb.w += gv[u].w; }
    #pragma unroll
    for (int p = 11; p >= 2; --p) {
        float4 v = tile[lq ^ (1u << (p - 2))];
        nb.x += v.x; nb.y += v.y; nb.z += v.z; nb.w += v.w;
    }
    nb.x += own.z; nb.y += own.w; nb.z += own.x; nb.w += own.y;
    nb.x += own.y; nb.y += own.x; nb.z += own.w; nb.w += own.z;
    float4 m;
    m.x = prevscale * fmaf(s, nb.x, own.x);
    m.y = prevscale * fmaf(s, nb.y, own.y);
    m.z = prevscale * fmaf(s, nb.z, own.z);
    m.w = prevscale * fmaf(s, nb.w, own.w);
    float4 o;
    if (LAYER < 2) {
        float gn = gamma[LAYER + 1];
        float4 c = ((const float4*)costs)[i4];
        o.x = m.x * cosf(gn * c.x); o.y = m.y * cosf(gn * c.y);
        o.z = m.z * cosf(gn * c.z); o.w = m.w * cosf(gn * c.w);
    } else o = m;
    if (ALOUT) ((float4*)pout)[i4] = o;
    else {
        pout[4u * i4 + 0] = o.x; pout[4u * i4 + 1] = o.y;
        pout[4u * i4 + 2] = o.z; pout[4u * i4 + 3] = o.w;
    }
    double ss = (double)m.x * m.x + (double)m.y * m.y + (double)m.z * m.z + (double)m.w * m.w;
    #pragma unroll
    for (int off = 32; off > 0; off >>= 1) ss += __shfl_down(ss, off);
    int wid = threadIdx.x >> 6;
    if ((threadIdx.x & 63) == 0) dpart[wid] = ss;
    __syncthreads();
    if (threadIdx.x == 0) {
        double tt = 0.0;
        #pragma unroll
        for (int w = 0; w < 16; ++w) tt += dpart[w];
        atomicAdd(&scal[LAYER], tt);
    }
}

// ---------------------------------------------------------------------------
// Fused probs + top-k stage 1 + (last block) stage 2 merge & readout.
// Identical to the validated R4/R10 version.
// ---------------------------------------------------------------------------
template <bool ALIN>
__global__ __launch_bounds__(256) void k_ptop(const float* __restrict__ A,
                                              const double* __restrict__ scal2,
                                              const float* __restrict__ costs,
                                              float* __restrict__ out,
                                              unsigned long long* __restrict__ cand,
                                              unsigned* __restrict__ ctr) {
    __shared__ unsigned long long warr[4];
    __shared__ int lastblk;
    __shared__ unsigned topi[TOPK];
    __shared__ float topc[TOPK];
    const int tid = threadIdx.x;
    float* probs_out = out + 21;
    unsigned b4 = blockIdx.x * 1024u;   // float4 base
    float scale = (float)(1.0 / sqrt(*scal2));

    unsigned long long k[16];
    #pragma unroll
    for (int u = 0; u < 4; ++u) {
        unsigned j4 = b4 + (unsigned)tid + 256u * u;
        float4 v;
        if (ALIN) v = ((const float4*)A)[j4];
        else {
            v.x = A[4u * j4 + 0]; v.y = A[4u * j4 + 1];
            v.z = A[4u * j4 + 2]; v.w = A[4u * j4 + 3];
        }
        float4 p;
        p.x = v.x * scale; p.x *= p.x;
        p.y = v.y * scale; p.y *= p.y;
        p.z = v.z * scale; p.z *= p.z;
        p.w = v.w * scale; p.w *= p.w;
        unsigned e0 = 4u * j4;
        probs_out[e0 + 0] = p.x; probs_out[e0 + 1] = p.y;
        probs_out[e0 + 2] = p.z; probs_out[e0 + 3] = p.w;
        k[4 * u + 0] = ((unsigned long long)__float_as_uint(p.x) << 32) | (unsigned long long)(0xFFFFFFFFu - (e0 + 0));
        k[4 * u + 1] = ((unsigned long long)__float_as_uint(p.y) << 32) | (unsigned long long)(0xFFFFFFFFu - (e0 + 1));
        k[4 * u + 2] = ((unsigned long long)__float_as_uint(p.z) << 32) | (unsigned long long)(0xFFFFFFFFu - (e0 + 2));
        k[4 * u + 3] = ((unsigned long long)__float_as_uint(p.w) << 32) | (unsigned long long)(0xFFFFFFFFu - (e0 + 3));
    }

    for (int r = 0; r < TOPK; ++r) {
        unsigned long long loc = 0ull;
        #pragma unroll
        for (int j = 0; j < 16; ++j) if (k[j] > loc) loc = k[j];
        #pragma unroll
        for (int off = 32; off > 0; off >>= 1) {
            unsigned long long o = __shfl_down(loc, off);
            if (o > loc) loc = o;
        }
        if ((tid & 63) == 0) warr[tid >> 6] = loc;
        __syncthreads();
        unsigned long long win = warr[0];
        if (warr[1] > win) win = warr[1];
        if (warr[2] > win) win = warr[2];
        if (warr[3] > win) win = warr[3];
        __syncthreads();
        #pragma unroll
        for (int j = 0; j < 16; ++j) if (k[j] == win) k[j] = 0ull;
        if (tid == 0) cand[blockIdx.x * TOPK + r] = win;
    }

    // ---- last-block ticket ----
    __threadfence();
    if (tid == 0) {
        unsigned old = atomicAdd(ctr, 1u);
        lastblk = (old == NB1 - 1) ? 1 : 0;
    }
    __syncthreads();
    if (!lastblk) return;
    __threadfence();

    // ---- stage 2: merge NCAND candidates with this one block ----
    unsigned long long c2[TOPK];
    #pragma unroll
    for (int u = 0; u < TOPK; ++u) c2[u] = cand[tid + 256 * u];

    for (int r = 0; r < TOPK; ++r) {
        unsigned long long loc = 0ull;
        #pragma unroll
        for (int u = 0; u < TOPK; ++u) if (c2[u] > loc) loc = c2[u];
        #pragma unroll
        for (int off = 32; off > 0; off >>= 1) {
            unsigned long long o = __shfl_down(loc, off);
            if (o > loc) loc = o;
        }
        if ((tid & 63) == 0) warr[tid >> 6] = loc;
        __syncthreads();
        unsigned long long win = warr[0];
        if (warr[1] > win) win = warr[1];
        if (warr[2] > win) win = warr[2];
        if (warr[3] > win) win = warr[3];
        __syncthreads();
        #pragma unroll
        for (int u = 0; u < TOPK; ++u) if (c2[u] == win) c2[u] = 0ull;
        if (tid == 0) topi[r] = 0xFFFFFFFFu - (unsigned)(win & 0xFFFFFFFFull);
        __syncthreads();
    }

    const unsigned S = NSTATES;
    if (tid < TOPK * NV) {
        int kk = tid / NV, vv = tid % NV;
        out[21 + S + (unsigned)tid] = (float)((topi[kk] >> (NV - 1 - vv)) & 1u);
    }
    if (tid < TOPK) {
        float c = costs[topi[tid]];
        topc[tid] = c;
        out[21 + S + TOPK * NV + (unsigned)tid] = c;
    }
    __syncthreads();
    if (tid == 0) {
        int best = 0;
        for (int kk = 1; kk < TOPK; ++kk)
            if (topc[kk] < topc[best]) best = kk;
        unsigned gi = topi[best];
        for (int vv = 0; vv < NV; ++vv)
            out[vv] = (float)((gi >> (NV - 1 - vv)) & 1u);
        out[NV] = topc[best];
    }
}

extern "C" void kernel_launch(void* const* d_in, const int* in_sizes, int n_in,
                              void* d_out_, int out_size, void* d_ws, size_t ws_size,
                              hipStream_t stream) {
    (void)in_sizes; (void)n_in; (void)out_size;
    const float* C     = (const float*)d_in[0];
    const float* beta  = (const float*)d_in[1];
    const float* gamma = (const float*)d_in[2];
    float* out = (float*)d_out_;
    char* ws = (char*)d_ws;
    const size_t S4 = (size_t)NSTATES * sizeof(float);   // 4 MB
    const size_t S2 = (size_t)NSTATES * 2;               // 2 MB (fp16)

    double* scal = (double*)ws;                                   // 8 doubles
    unsigned* ctr = (unsigned*)(ws + 64);
    unsigned long long* cand = (unsigned long long*)(ws + 1024);  // 20 KB
    float* costs = (float*)(ws + 32768);
    float* A     = (float*)(ws + 32768 + S4);                     // ph0 / pm2
    float* B     = (float*)(ws + 32768 + 2 * S4);                 // pm1 / m2
    h4*    Ah    = (h4*)(ws + 32768 + 3 * S4);                    // fp16 shadow
    h4*    Bh    = (h4*)(ws + 32768 + 3 * S4 + S2);

    const size_t need_half = 32768 + 3 * S4 + 2 * S2;   // ~16.03 MB
    const size_t need_f32  = 32768 + 3 * S4;            // ~12.03 MB

    if (ws_size >= need_half) {
        // -------- primary: hybrid fp16-gather pipeline --------
        k_costs<true><<<256, 512, 0, stream>>>(C, costs, A, Ah, gamma, scal, ctr);
        // mix0: A(ph0)+Ah -> B(pm1)+Bh
        k_mixh<0><<<256, 1024, 0, stream>>>(A, Ah, costs, B, Bh, gamma, beta, scal);
        // mix1: B(pm1)+Bh -> A(pm2)+Ah
        k_mixh<1><<<256, 1024, 0, stream>>>(B, Bh, costs, A, Ah, gamma, beta, scal);
        // mix2: A(pm2)+Ah -> B(m2)
        k_mixh<2><<<256, 1024, 0, stream>>>(A, Ah, costs, B, nullptr, gamma, beta, scal);
        k_ptop<true><<<NB1, 256, 0, stream>>>(B, scal + 2, costs, out, cand, ctr);
    } else {
        // -------- fallback: validated R10 f32 pipeline --------
        bool wsbig = (ws_size >= need_f32);
        float* Bf = wsbig ? B : (out + 21);
        k_costs<false><<<256, 512, 0, stream>>>(C, costs, A, nullptr, gamma, scal, ctr);
        if (wsbig) {
            k_mix<0, true, true ><<<256, 1024, 0, stream>>>(A, costs, Bf, gamma, beta, scal);
            k_mix<1, true, true ><<<256, 1024, 0, stream>>>(Bf, costs, A, gamma, beta, scal);
            k_mix<2, true, true ><<<256, 1024, 0, stream>>>(A, costs, Bf, gamma, beta, scal);
            k_ptop<true ><<<NB1, 256, 0, stream>>>(Bf, scal + 2, costs, out, cand, ctr);
        } else {
            k_mix<0, true, false><<<256, 1024, 0, stream>>>(A, costs, Bf, gamma, beta, scal);
            k_mix<1, false, true><<<256, 1024, 0, stream>>>(Bf, costs, A, gamma, beta, scal);
            k_mix<2, true, false><<<256, 1024, 0, stream>>>(A, costs, Bf, gamma, beta, scal);
            k_ptop<false><<<NB1, 256, 0, stream>>>(Bf, scal + 2, costs, out, cand, ctr);
        }
    }
}